// Round 10
// baseline (265.988 us; speedup 1.0000x reference)
//
#include <hip/hip_runtime.h>

#define EPSB 1e-3f

typedef _Float16 half8 __attribute__((ext_vector_type(8)));
typedef _Float16 half4 __attribute__((ext_vector_type(4)));
typedef float f32x4 __attribute__((ext_vector_type(4)));

// ---------------- prep: weights -> MFMA-fragment order (f16), BN fold ----------------
__global__ __launch_bounds__(256, 4)
void k_prep(const float* __restrict__ W1, const float* __restrict__ W2,
            const float* __restrict__ b1, const float* __restrict__ g1,
            const float* __restrict__ be1, const float* __restrict__ mu1,
            const float* __restrict__ v1,
            const float* __restrict__ b2, const float* __restrict__ g2,
            const float* __restrict__ be2, const float* __restrict__ mu2,
            const float* __restrict__ v2,
            _Float16* __restrict__ W1F, _Float16* __restrict__ W2F,
            float* __restrict__ ST)
{
    int t = blockIdx.x * 256 + threadIdx.x;
    if (t < 5 * 4 * 64 * 8) {                 // W1F
        int k = t & 7, lane = (t >> 3) & 63, snt = t >> 9;
        int s = snt >> 2, ct = snt & 3;
        int quad = lane >> 4, n16 = lane & 15;
        int tap = 2 * s + (quad >> 1);
        int ci  = (quad & 1) * 8 + k;
        int co  = ct * 16 + n16;
        float v = (tap < 9) ? W1[(tap * 16 + ci) * 64 + co] : 0.f;
        W1F[t] = (_Float16)v;
        return;
    }
    t -= 5 * 4 * 64 * 8;
    if (t < 18 * 4 * 64 * 8) {                // W2F
        int k = t & 7, lane = (t >> 3) & 63, snt = t >> 9;
        int s = snt >> 2, ct = snt & 3;
        int quad = lane >> 4, n16 = lane & 15;
        int tap = s >> 1;
        int ci  = (s & 1) * 32 + quad * 8 + k;
        int co  = ct * 16 + n16;
        W2F[t] = (_Float16)W2[(tap * 64 + ci) * 64 + co];
        return;
    }
    t -= 18 * 4 * 64 * 8;
    if (t < 256) {
        int c = t & 63, sel = t >> 6;
        if (sel == 0)      ST[c]       = g1[c] * rsqrtf(v1[c] + EPSB);
        else if (sel == 1) ST[64 + c]  = (b1[c] - mu1[c]) * (g1[c] * rsqrtf(v1[c] + EPSB)) + be1[c];
        else if (sel == 2) ST[128 + c] = g2[c] * rsqrtf(v2[c] + EPSB);
        else               ST[192 + c] = (b2[c] - mu2[c]) * (g2[c] * rsqrtf(v2[c] + EPSB)) + be2[c];
    }
}

// ================= fused conv1+conv2 (R10: LDS = sC1 only, 4 blocks/CU) =================
// Phase B: conv1 reads mr DIRECTLY from global (26 KB tile, L1/L2-resident;
//          3-deep pf pipeline, 2-deep wf) -> sC1 swizzled stride-64. No sMR stage.
// Phase C: channel-split waves (wave w owns ct=w, all 128 px), 8-deep wf, 2-deep pf.
// Epilogue: NO LDS — BF stored straight from hv registers (half4/lane; L2 merges
//          the 4 ctw-waves' 8B chunks into full lines); fused s2 via __shfl_xor(1):
//          lane pair (n16 even/odd) holds the 2x2 cell's two columns, each lane
//          needs only pet channel ctw*4+quad. ONE barrier total.
// LDS: 33,792 B -> 4 blocks/CU (16 waves) under __launch_bounds__(256,4).
// R8 lesson honored: nothing held in registers across the barrier.
__global__ __launch_bounds__(256, 4)
void k_convf(const float* __restrict__ mr, const _Float16* __restrict__ W1F,
             const _Float16* __restrict__ W2F, const float* __restrict__ ST,
             const float* __restrict__ pet,
             _Float16* __restrict__ BF, float* __restrict__ S2)
{
    __shared__ __align__(16) _Float16 sC1[4 * 66 * 64];     // 33,792 B
    const int tid = threadIdx.x;
    const int b  = blockIdx.y;
    const int r0 = (blockIdx.x >> 2) * 2;
    const int q0 = (blockIdx.x & 3) * 64;

    const int w = tid >> 6, lane = tid & 63;
    const int n16 = lane & 15, quad = lane >> 4;

    // ---- Phase B: conv1 (global-direct mr reads) into sC1 ----
    {
        const _Float16* Wl1 = W1F + lane * 8;
        const int ci0 = (quad & 1) * 8;
        #pragma unroll
        for (int k = 0; k < 5; ++k) {
            const int g  = w + 4 * k;          // 20 groups, 5 per wave
            const int y  = g / 5;
            const int xi = g % 5;
            const int x0 = xi * 13 - ((xi >> 2) << 1);   // 0,13,26,39,50
            const int px = x0 + n16;                     // 0..65

            f32x4 a1[4];
            #pragma unroll
            for (int ct = 0; ct < 4; ++ct) a1[ct] = (f32x4){0.f, 0.f, 0.f, 0.f};

            half8 wf1[2][4], pf1[3];
            auto loadw1 = [&](int s, int buf) {
                #pragma unroll
                for (int ct = 0; ct < 4; ++ct)
                    wf1[buf][ct] = *(const half8*)(Wl1 + (s * 4 + ct) * 512);
            };
            auto loadp1 = [&](int s, int buf) {
                int tap  = 2 * s + (quad >> 1);
                int tapc = tap > 8 ? 8 : tap;            // tap 9 -> zero weight, any read
                int dy = tapc / 3, dx = tapc % 3;
                int rr = r0 + y + dy - 2, qg = q0 + px + dx - 2;
                half8 h = (half8)(_Float16)0.f;
                if ((unsigned)rr < 256u && (unsigned)qg < 256u) {
                    const float* src = mr + ((b * 256 + rr) * 256 + qg) * 16 + ci0;
                    float4 v0 = *(const float4*)src;
                    float4 v1 = *(const float4*)(src + 4);
                    h = (half8){(_Float16)v0.x, (_Float16)v0.y, (_Float16)v0.z, (_Float16)v0.w,
                                (_Float16)v1.x, (_Float16)v1.y, (_Float16)v1.z, (_Float16)v1.w};
                }
                pf1[buf] = h;
            };
            loadw1(0, 0); loadw1(1, 1);
            loadp1(0, 0); loadp1(1, 1); loadp1(2, 2);
            #pragma unroll
            for (int s = 0; s < 5; ++s) {
                #pragma unroll
                for (int ct = 0; ct < 4; ++ct)
                    a1[ct] = __builtin_amdgcn_mfma_f32_16x16x32_f16(wf1[s & 1][ct], pf1[s % 3], a1[ct], 0, 0, 0);
                if (s + 2 < 5) loadw1(s + 2, s & 1);
                if (s + 3 < 5) loadp1(s + 3, s % 3);
            }

            // BN + ReLU; zero outside image (conv2 SAME padding); store swizzled
            const bool valid = ((unsigned)(r0 - 1 + y) < 256u) && ((unsigned)(q0 - 1 + px) < 256u);
            #pragma unroll
            for (int ct = 0; ct < 4; ++ct) {
                int co0 = ct * 16 + quad * 4;
                f32x4 sc = *(const f32x4*)&ST[co0];
                f32x4 sh = *(const f32x4*)&ST[64 + co0];
                half4 h;
                #pragma unroll
                for (int j = 0; j < 4; ++j)
                    h[j] = (_Float16)fmaxf(a1[ct][j] * sc[j] + sh[j], 0.f);
                if (!valid) h = (half4)(_Float16)0.f;
                int slot = ct * 2 + (quad >> 1);
                *(half4*)&sC1[(y * 66 + px) * 64 + ((slot ^ (px & 7)) << 3) + (quad & 1) * 4] = h;
            }
        }
    }
    __syncthreads();   // sC1 ready — the ONLY barrier

    // ---- Phase C: conv2, channel-split waves, 8-deep wf prefetch ----
    const int ctw = w;                      // wave owns ct = w (channels ctw*16..+15)
    const _Float16* Wl = W2F + lane * 8;

    f32x4 acc[2][4];   // [rr][qt]: 2 rows x 4 q-groups of 16
    #pragma unroll
    for (int i = 0; i < 2; ++i)
        #pragma unroll
        for (int j = 0; j < 4; ++j) acc[i][j] = (f32x4){0.f, 0.f, 0.f, 0.f};

    half8 wfb[8];         // 8-deep wf prefetch (4 VGPR each)
    half8 pfb[2][2][4];   // 2-deep pf prefetch [buf][rr][qt]
    auto loadw = [&](int s, int buf) {
        wfb[buf] = *(const half8*)(Wl + (s * 4 + ctw) * 512);
    };
    auto loadp = [&](int s, int buf) {
        const int tap = s >> 1;
        const int dy = tap / 3, dx = tap % 3;
        const int slot = (s & 1) * 4 + quad;       // channel-group slot before swizzle
        const int sxm = (n16 + dx) & 7;            // col&7 (qt*16 is 0 mod 8)
        #pragma unroll
        for (int rr = 0; rr < 2; ++rr)
            #pragma unroll
            for (int qt = 0; qt < 4; ++qt)
                pfb[buf][rr][qt] = *(const half8*)&sC1[((rr + dy) * 66 + qt * 16 + n16 + dx) * 64 + ((slot ^ sxm) << 3)];
    };
    loadw(0, 0); loadw(1, 1); loadw(2, 2); loadw(3, 3);
    loadw(4, 4); loadw(5, 5); loadw(6, 6); loadw(7, 7);
    loadp(0, 0); loadp(1, 1);
    #pragma unroll
    for (int s = 0; s < 18; ++s) {
        const int bw = s & 7, bp = s & 1;
        #pragma unroll
        for (int rr = 0; rr < 2; ++rr)
            #pragma unroll
            for (int qt = 0; qt < 4; ++qt)
                acc[rr][qt] = __builtin_amdgcn_mfma_f32_16x16x32_f16(wfb[bw], pfb[bp][rr][qt], acc[rr][qt], 0, 0, 0);
        if (s + 8 < 18) loadw(s + 8, bw);
        if (s + 2 < 18) loadp(s + 2, bp);
    }

    // BN + softmax(4 in-lane) + mask -> registers (wave's co0 = ctw*16+quad*4)
    const int co0 = ctw * 16 + quad * 4;
    half4 hv[2][4];    // [rr][qt]
    {
        f32x4 sc = *(const f32x4*)&ST[128 + co0];
        f32x4 sh = *(const f32x4*)&ST[192 + co0];
        #pragma unroll
        for (int rr = 0; rr < 2; ++rr)
            #pragma unroll
            for (int qt = 0; qt < 4; ++qt) {
                float z0 = acc[rr][qt][0] * sc[0] + sh[0];
                float z1 = acc[rr][qt][1] * sc[1] + sh[1];
                float z2 = acc[rr][qt][2] * sc[2] + sh[2];
                float z3 = acc[rr][qt][3] * sc[3] + sh[3];
                float mx = fmaxf(fmaxf(z0, z1), fmaxf(z2, z3));
                float e0 = __expf(z0 - mx), e1 = __expf(z1 - mx);
                float e2 = __expf(z2 - mx), e3 = __expf(z3 - mx);
                float inv = __builtin_amdgcn_rcpf((e0 + e1) + (e2 + e3));
                float p0 = e0 * inv, p1 = e1 * inv, p2 = e2 * inv, p3 = e3 * inv;
                half4 h;
                h[0] = (_Float16)(p0 > 1e-5f ? p0 : 0.f);
                h[1] = (_Float16)(p1 > 1e-5f ? p1 : 0.f);
                h[2] = (_Float16)(p2 > 1e-5f ? p2 : 0.f);
                h[3] = (_Float16)(p3 > 1e-5f ? p3 : 0.f);
                hv[rr][qt] = h;
            }
    }

    // BF store: direct from registers, half4 (8 B) per (rr,qt).
    // Within a lane-quad column the 4 ctw-waves fill each 32 B run; L2 merges.
    #pragma unroll
    for (int rr = 0; rr < 2; ++rr)
        #pragma unroll
        for (int qt = 0; qt < 4; ++qt) {
            int ql = qt * 16 + n16;
            *(half4*)(BF + (((b * 256 + r0 + rr) * 256 + q0 + ql) * 64 + co0)) = hv[rr][qt];
        }

    // fused s2 in registers: lane pair (n16 even/odd) = the 2x2 cell's two columns.
    // pet channel for this lane's 4 channels (co0..co0+3) is pc = co0>>2.
    {
        const int pc = co0 >> 2;           // = ctw*4 + quad
        #pragma unroll
        for (int qt = 0; qt < 4; ++qt) {
            int ql = qt * 16 + n16;
            float p0 = pet[((b * 256 + r0 + 0) * 256 + q0 + ql) * 16 + pc];
            float p1 = pet[((b * 256 + r0 + 1) * 256 + q0 + ql) * 16 + pc];
            f32x4 dns, kps;
            #pragma unroll
            for (int j = 0; j < 4; ++j) {
                float v0 = (float)hv[0][qt][j];
                float v1 = (float)hv[1][qt][j];
                float dnp = v0 + v1;
                float kpp = fmaf(p0, v0, p1 * v1);
                dns[j] = dnp + __shfl_xor(dnp, 1, 64);
                kps[j] = kpp + __shfl_xor(kpp, 1, 64);
            }
            int cell = qt * 8 + (n16 >> 1);
            int jb = (n16 & 1) * 2;        // even lane: ch co0+0,1 ; odd: co0+2,3
            float* o = S2 + 2 * ((size_t)(((b * 128 + (r0 >> 1)) * 128 + (q0 >> 1) + cell) * 64) + co0 + jb);
            *(float4*)o = make_float4(dns[jb], kps[jb], dns[jb + 1], kps[jb + 1]);
        }
    }
}

// ---------------- ratio: j-paired — 2 outputs per thread, 6 shared loads/row ----------------
__global__ __launch_bounds__(256, 8)
void k_ratio(const float* __restrict__ S2, float* __restrict__ RATIO)
{
    int t = blockIdx.x * 256 + threadIdx.x;   // 3*64*32*64 threads
    int cf = t & 63;
    int j2 = (t >> 6) & 31;
    int i  = (t >> 11) & 63;
    int b  = t >> 17;
    float dn0 = 0.f, kp0 = 0.f, dn1 = 0.f, kp1 = 0.f;
    #pragma unroll
    for (int u = 0; u < 4; ++u) {
        int r2 = 2 * i - 1 + u;
        if ((unsigned)r2 >= 128u) continue;
        const float* rowp = S2 + 2 * (((size_t)(b * 128 + r2) * 128) * 64 + cf);
        float2 sv[6];
        #pragma unroll
        for (int tq = 0; tq < 6; ++tq) {
            int q2 = 4 * j2 - 1 + tq;
            sv[tq] = ((unsigned)q2 < 128u) ? *(const float2*)(rowp + q2 * 128)
                                           : make_float2(0.f, 0.f);
        }
        dn0 += sv[0].x; kp0 += sv[0].y;
        dn0 += sv[1].x; kp0 += sv[1].y;
        dn0 += sv[2].x; kp0 += sv[2].y;
        dn0 += sv[3].x; kp0 += sv[3].y;
        dn1 += sv[2].x; kp1 += sv[2].y;
        dn1 += sv[3].x; kp1 += sv[3].y;
        dn1 += sv[4].x; kp1 += sv[4].y;
        dn1 += sv[5].x; kp1 += sv[5].y;
    }
    size_t base = ((size_t)(b * 64 + i) * 64 + 2 * j2) * 64 + cf;
    RATIO[base]      = (dn0 == 0.f) ? 0.f : 0.25f * kp0 * __builtin_amdgcn_rcpf(dn0);
    RATIO[base + 64] = (dn1 == 0.f) ? 0.f : 0.25f * kp1 * __builtin_amdgcn_rcpf(dn1);
}

// ---------------- out: 4-row bands share one sU staging ----------------
__global__ __launch_bounds__(256, 4)
void k_out(const _Float16* __restrict__ BF, const float* __restrict__ RATIO,
           float* __restrict__ out)
{
    __shared__ __align__(16) float sU[64 * 68];   // [j][cf], row padded to 68
    const int tid = threadIdx.x;
    const int g = blockIdx.x % 65;
    const int b = blockIdx.x / 65;
    const int rf = (g == 0) ? 0 : 4 * g - 2;           // band first row
    const int nr = (g == 0 || g == 64) ? 2 : 4;        // band size

    const int i0 = (rf <= 253) ? 2 * ((rf + 2) >> 3)       : -1;
    const int i1 = (rf >= 2)   ? 2 * ((rf - 2) >> 3) + 1   : -1;

    for (int idx = tid; idx < 1024; idx += 256) {      // 1024 float4s
        int j = idx >> 4, c4 = idx & 15;
        float4 a = make_float4(0.f, 0.f, 0.f, 0.f);
        if (i0 >= 0) a = *(const float4*)&RATIO[(((b * 64 + i0) * 64 + j) << 6) + 4 * c4];
        float4 bb = make_float4(0.f, 0.f, 0.f, 0.f);
        if (i1 >= 0) bb = *(const float4*)&RATIO[(((b * 64 + i1) * 64 + j) << 6) + 4 * c4];
        *(float4*)&sU[j * 68 + 4 * c4] = make_float4(a.x + bb.x, a.y + bb.y, a.z + bb.z, a.w + bb.w);
    }
    __syncthreads();

    const int q = tid;
    const int j0 = (q <= 253) ? 2 * ((q + 2) >> 3)     : -1;
    const int j1 = (q >= 2)   ? 2 * ((q - 2) >> 3) + 1 : -1;

    for (int rr = 0; rr < nr; ++rr) {
        const int r = rf + rr;
        const half8* bfp = (const half8*)(BF + ((size_t)(b * 256 + r) * 256 + q) * 64);
        float o[16];
        #pragma unroll
        for (int c = 0; c < 16; ++c) o[c] = 0.f;

        #pragma unroll
        for (int c2 = 0; c2 < 8; ++c2) {
            half8 bf8 = bfp[c2];
            float s0 = 0.f, s1 = 0.f;
            #pragma unroll
            for (int pj = 0; pj < 2; ++pj) {
                int jj = pj ? j1 : j0;
                if (jj < 0) continue;
                const float* up = &sU[jj * 68 + 8 * c2];
                s0 += (float)bf8[0] * up[0] + (float)bf8[1] * up[1]
                    + (float)bf8[2] * up[2] + (float)bf8[3] * up[3];
                s1 += (float)bf8[4] * up[4] + (float)bf8[5] * up[5]
                    + (float)bf8[6] * up[6] + (float)bf8[7] * up[7];
            }
            o[2 * c2]     = s0;
            o[2 * c2 + 1] = s1;
        }
        float* op = out + ((size_t)(b * 256 + r) * 256 + q) * 16;
        #pragma unroll
        for (int m = 0; m < 4; ++m)
            *(float4*)(op + 4 * m) = make_float4(o[4*m], o[4*m+1], o[4*m+2], o[4*m+3]);
    }
}

extern "C" void kernel_launch(void* const* d_in, const int* in_sizes, int n_in,
                              void* d_out, int out_size, void* d_ws, size_t ws_size,
                              hipStream_t stream) {
    const float* mr  = (const float*)d_in[0];
    const float* pet = (const float*)d_in[1];
    const float* W1  = (const float*)d_in[2];
    const float* b1  = (const float*)d_in[3];
    const float* g1  = (const float*)d_in[4];
    const float* be1 = (const float*)d_in[5];
    const float* mu1 = (const float*)d_in[6];
    const float* v1  = (const float*)d_in[7];
    const float* W2  = (const float*)d_in[8];
    const float* b2  = (const float*)d_in[9];
    const float* g2  = (const float*)d_in[10];
    const float* be2 = (const float*)d_in[11];
    const float* mu2 = (const float*)d_in[12];
    const float* v2  = (const float*)d_in[13];

    // workspace layout (bytes):
    //   [0,        25165824)  BF  f16 (3*256*256*64)
    //   [25165824, 50331648)  S2  fp32 (3*128*128*64*2)
    //   [50331648, 53477376)  RATIO fp32 (3*64*64*64)
    //   [53477376, 53497856)  W1F f16
    //   [53497856, 53571584)  W2F f16
    //   [53571584, 53572608)  ST  fp32
    char* ws = (char*)d_ws;
    _Float16* BF    = (_Float16*)(ws);
    float*    S2    = (float*)(ws + 25165824);
    float*    RATIO = (float*)(ws + 50331648);
    _Float16* W1F   = (_Float16*)(ws + 53477376);
    _Float16* W2F   = (_Float16*)(ws + 53497856);
    float*    ST    = (float*)(ws + 53571584);
    float*    out   = (float*)d_out;

    dim3 blk(256);
    k_prep<<<185, blk, 0, stream>>>(W1, W2, b1, g1, be1, mu1, v1,
                                    b2, g2, be2, mu2, v2, W1F, W2F, ST);
    k_convf<<<dim3(512, 3), blk, 0, stream>>>(mr, W1F, W2F, ST, pet, BF, S2);
    k_ratio<<<1536, blk, 0, stream>>>(S2, RATIO);
    k_out<<<195, blk, 0, stream>>>(BF, RATIO, out);
}

// Round 11
// 157.623 us; speedup vs baseline: 1.6875x; 1.6875x over previous
//
#include <hip/hip_runtime.h>

#define EPSB 1e-3f

typedef _Float16 half8 __attribute__((ext_vector_type(8)));
typedef _Float16 half4 __attribute__((ext_vector_type(4)));
typedef float f32x4 __attribute__((ext_vector_type(4)));

// ---------------- prep: weights -> MFMA-fragment order (f16), BN fold ----------------
__global__ __launch_bounds__(256, 4)
void k_prep(const float* __restrict__ W1, const float* __restrict__ W2,
            const float* __restrict__ b1, const float* __restrict__ g1,
            const float* __restrict__ be1, const float* __restrict__ mu1,
            const float* __restrict__ v1,
            const float* __restrict__ b2, const float* __restrict__ g2,
            const float* __restrict__ be2, const float* __restrict__ mu2,
            const float* __restrict__ v2,
            _Float16* __restrict__ W1F, _Float16* __restrict__ W2F,
            float* __restrict__ ST)
{
    int t = blockIdx.x * 256 + threadIdx.x;
    if (t < 5 * 4 * 64 * 8) {                 // W1F
        int k = t & 7, lane = (t >> 3) & 63, snt = t >> 9;
        int s = snt >> 2, ct = snt & 3;
        int quad = lane >> 4, n16 = lane & 15;
        int tap = 2 * s + (quad >> 1);
        int ci  = (quad & 1) * 8 + k;
        int co  = ct * 16 + n16;
        float v = (tap < 9) ? W1[(tap * 16 + ci) * 64 + co] : 0.f;
        W1F[t] = (_Float16)v;
        return;
    }
    t -= 5 * 4 * 64 * 8;
    if (t < 18 * 4 * 64 * 8) {                // W2F
        int k = t & 7, lane = (t >> 3) & 63, snt = t >> 9;
        int s = snt >> 2, ct = snt & 3;
        int quad = lane >> 4, n16 = lane & 15;
        int tap = s >> 1;
        int ci  = (s & 1) * 32 + quad * 8 + k;
        int co  = ct * 16 + n16;
        W2F[t] = (_Float16)W2[(tap * 64 + ci) * 64 + co];
        return;
    }
    t -= 18 * 4 * 64 * 8;
    if (t < 256) {
        int c = t & 63, sel = t >> 6;
        if (sel == 0)      ST[c]       = g1[c] * rsqrtf(v1[c] + EPSB);
        else if (sel == 1) ST[64 + c]  = (b1[c] - mu1[c]) * (g1[c] * rsqrtf(v1[c] + EPSB)) + be1[c];
        else if (sel == 2) ST[128 + c] = g2[c] * rsqrtf(v2[c] + EPSB);
        else               ST[192 + c] = (b2[c] - mu2[c]) * (g2[c] * rsqrtf(v2[c] + EPSB)) + be2[c];
    }
}

// ================= fused conv1+conv2 (R9 structure — verified 160.0 µs best) =================
// Phase A: stage mr rows r0-2..r0+3, cols q0-2..q0+65 (6x68x16 f16), stride 20, into sMR.
// Phase B: conv1 (+BN+ReLU) -> sC1 (swizzled stride-64), 20 groups of 16 px.
// Phase C: channel-split waves (wave w owns ct=w, all 128 px), 8-deep wf prefetch,
//          2-deep pf; 8 MFMAs/step; s_setprio(1) around the MFMA cluster (T5 —
//          waves run the loop barrier-free/independently, the favorable regime).
// Epilogue: BF tile in dead sMR region (no extra barrier), coalesced BF store +
//          fused s2 cell sums.
// LDS: 16,384 (sMR/sBF union) + 33,792 (sC1) = 50,176 B -> 3 blocks/CU.
// LESSONS (R8/R10): do NOT cap at 4 waves/SIMD — this kernel's register footprint
// spills past 128 VGPR (WRITE_SIZE 49 -> 220+ MB, 2-5x slowdown). 3 blocks/CU is
// the occupancy ceiling for this structure.
#define CIPM 20   // mr pixel stride in f16 (40 B)
__global__ __launch_bounds__(256, 3)
void k_convf(const float* __restrict__ mr, const _Float16* __restrict__ W1F,
             const _Float16* __restrict__ W2F, const float* __restrict__ ST,
             const float* __restrict__ pet,
             _Float16* __restrict__ BF, float* __restrict__ S2)
{
    __shared__ __align__(16) _Float16 sMR[8192];            // 16,384 B: mr stage (8,160 used); aliased as BF tile in epilogue
    __shared__ __align__(16) _Float16 sC1[4 * 66 * 64];     // 33,792 B
    _Float16* const sBF = sMR;                              // epilogue alias
    const int tid = threadIdx.x;
    const int b  = blockIdx.y;
    const int r0 = (blockIdx.x >> 2) * 2;
    const int q0 = (blockIdx.x & 3) * 64;

    // ---- Phase A: stage mr ----
    for (int idx = tid; idx < 6 * 68 * 2; idx += 256) {
        int c = idx & 1, pp = idx >> 1;
        int p = pp % 68, dys = pp / 68;
        int rr = r0 + dys - 2, qg = q0 + p - 2;
        half8 h = (half8)(_Float16)0.f;
        if ((unsigned)rr < 256u && (unsigned)qg < 256u) {
            const float* src = mr + ((b * 256 + rr) * 256 + qg) * 16 + c * 8;
            float4 v0 = *(const float4*)src;
            float4 v1 = *(const float4*)(src + 4);
            h = (half8){(_Float16)v0.x, (_Float16)v0.y, (_Float16)v0.z, (_Float16)v0.w,
                        (_Float16)v1.x, (_Float16)v1.y, (_Float16)v1.z, (_Float16)v1.w};
        }
        *(half8*)(&sMR[pp * CIPM + c * 8]) = h;
    }
    __syncthreads();

    const int w = tid >> 6, lane = tid & 63;
    const int n16 = lane & 15, quad = lane >> 4;

    // ---- Phase B: conv1 into sC1 ----
    {
        const _Float16* Wl1 = W1F + lane * 8;
        const int ci0 = (quad & 1) * 8;
        #pragma unroll
        for (int k = 0; k < 5; ++k) {
            const int g  = w + 4 * k;          // 20 groups, 5 per wave
            const int y  = g / 5;
            const int xi = g % 5;
            const int x0 = xi * 13 - ((xi >> 2) << 1);   // 0,13,26,39,50
            const int px = x0 + n16;                     // 0..65

            f32x4 a1[4];
            #pragma unroll
            for (int ct = 0; ct < 4; ++ct) a1[ct] = (f32x4){0.f, 0.f, 0.f, 0.f};

            half8 wf1[2][4], pf1[2];
            auto load1 = [&](int s, int buf) {
                int tap  = 2 * s + (quad >> 1);
                int tapc = tap > 8 ? 8 : tap;            // tap 9 -> zero weight, any read
                int dy = tapc / 3, dx = tapc % 3;
                #pragma unroll
                for (int ct = 0; ct < 4; ++ct)
                    wf1[buf][ct] = *(const half8*)(Wl1 + (s * 4 + ct) * 512);
                pf1[buf] = *(const half8*)&sMR[((y + dy) * 68 + px + dx) * CIPM + ci0];
            };
            load1(0, 0);
            load1(1, 1);
            #pragma unroll
            for (int s = 0; s < 5; ++s) {
                const int buf = s & 1;
                #pragma unroll
                for (int ct = 0; ct < 4; ++ct)
                    a1[ct] = __builtin_amdgcn_mfma_f32_16x16x32_f16(wf1[buf][ct], pf1[buf], a1[ct], 0, 0, 0);
                if (s + 2 < 5) load1(s + 2, buf);
            }

            // BN + ReLU; zero outside image (conv2 SAME padding); store swizzled
            const bool valid = ((unsigned)(r0 - 1 + y) < 256u) && ((unsigned)(q0 - 1 + px) < 256u);
            #pragma unroll
            for (int ct = 0; ct < 4; ++ct) {
                int co0 = ct * 16 + quad * 4;
                f32x4 sc = *(const f32x4*)&ST[co0];
                f32x4 sh = *(const f32x4*)&ST[64 + co0];
                half4 h;
                #pragma unroll
                for (int j = 0; j < 4; ++j)
                    h[j] = (_Float16)fmaxf(a1[ct][j] * sc[j] + sh[j], 0.f);
                if (!valid) h = (half4)(_Float16)0.f;
                int slot = ct * 2 + (quad >> 1);
                *(half4*)&sC1[(y * 66 + px) * 64 + ((slot ^ (px & 7)) << 3) + (quad & 1) * 4] = h;
            }
        }
    }
    __syncthreads();

    // ---- Phase C: conv2, channel-split waves, 8-deep wf prefetch ----
    const int ctw = w;                      // wave owns ct = w (channels ctw*16..+15)
    const _Float16* Wl = W2F + lane * 8;

    f32x4 acc[2][4];   // [rr][qt]: 2 rows x 4 q-groups of 16
    #pragma unroll
    for (int i = 0; i < 2; ++i)
        #pragma unroll
        for (int j = 0; j < 4; ++j) acc[i][j] = (f32x4){0.f, 0.f, 0.f, 0.f};

    half8 wfb[8];         // 8-deep wf prefetch (4 VGPR each)
    half8 pfb[2][2][4];   // 2-deep pf prefetch [buf][rr][qt]
    auto loadw = [&](int s, int buf) {
        wfb[buf] = *(const half8*)(Wl + (s * 4 + ctw) * 512);
    };
    auto loadp = [&](int s, int buf) {
        const int tap = s >> 1;
        const int dy = tap / 3, dx = tap % 3;
        const int slot = (s & 1) * 4 + quad;       // channel-group slot before swizzle
        const int sxm = (n16 + dx) & 7;            // col&7 (qt*16 is 0 mod 8)
        #pragma unroll
        for (int rr = 0; rr < 2; ++rr)
            #pragma unroll
            for (int qt = 0; qt < 4; ++qt)
                pfb[buf][rr][qt] = *(const half8*)&sC1[((rr + dy) * 66 + qt * 16 + n16 + dx) * 64 + ((slot ^ sxm) << 3)];
    };
    loadw(0, 0); loadw(1, 1); loadw(2, 2); loadw(3, 3);
    loadw(4, 4); loadw(5, 5); loadw(6, 6); loadw(7, 7);
    loadp(0, 0); loadp(1, 1);
    #pragma unroll
    for (int s = 0; s < 18; ++s) {
        const int bw = s & 7, bp = s & 1;
        __builtin_amdgcn_s_setprio(1);     // T5: favor MFMA-issuing wave (no intra-loop barriers -> waves independent)
        #pragma unroll
        for (int rr = 0; rr < 2; ++rr)
            #pragma unroll
            for (int qt = 0; qt < 4; ++qt)
                acc[rr][qt] = __builtin_amdgcn_mfma_f32_16x16x32_f16(wfb[bw], pfb[bp][rr][qt], acc[rr][qt], 0, 0, 0);
        __builtin_amdgcn_s_setprio(0);
        if (s + 8 < 18) loadw(s + 8, bw);
        if (s + 2 < 18) loadp(s + 2, bp);
    }

    // BN + softmax(4 in-lane) + mask -> registers (wave's co0 = ctw*16+quad*4)
    half4 hv[2][4];    // [rr][qt]
    {
        const int co0 = ctw * 16 + quad * 4;
        f32x4 sc = *(const f32x4*)&ST[128 + co0];
        f32x4 sh = *(const f32x4*)&ST[192 + co0];
        #pragma unroll
        for (int rr = 0; rr < 2; ++rr)
            #pragma unroll
            for (int qt = 0; qt < 4; ++qt) {
                float z0 = acc[rr][qt][0] * sc[0] + sh[0];
                float z1 = acc[rr][qt][1] * sc[1] + sh[1];
                float z2 = acc[rr][qt][2] * sc[2] + sh[2];
                float z3 = acc[rr][qt][3] * sc[3] + sh[3];
                float mx = fmaxf(fmaxf(z0, z1), fmaxf(z2, z3));
                float e0 = __expf(z0 - mx), e1 = __expf(z1 - mx);
                float e2 = __expf(z2 - mx), e3 = __expf(z3 - mx);
                float inv = __builtin_amdgcn_rcpf((e0 + e1) + (e2 + e3));
                float p0 = e0 * inv, p1 = e1 * inv, p2 = e2 * inv, p3 = e3 * inv;
                half4 h;
                h[0] = (_Float16)(p0 > 1e-5f ? p0 : 0.f);
                h[1] = (_Float16)(p1 > 1e-5f ? p1 : 0.f);
                h[2] = (_Float16)(p2 > 1e-5f ? p2 : 0.f);
                h[3] = (_Float16)(p3 > 1e-5f ? p3 : 0.f);
                hv[rr][qt] = h;
            }
    }

    // store hv -> sBF (dead sMR region). No protection barrier needed.
    {
        const int slotw = ctw * 2 + (quad >> 1);   // co0 >> 3
        const int sub   = (quad & 1) * 4;          // co0 & 7
        #pragma unroll
        for (int rr = 0; rr < 2; ++rr)
            #pragma unroll
            for (int qt = 0; qt < 4; ++qt) {
                int ql = qt * 16 + n16;
                *(half4*)(&sBF[(rr * 64 + ql) * 64 + ((slotw ^ (ql & 7)) << 3) + sub]) = hv[rr][qt];
            }
    }
    __syncthreads();   // sBF complete -> cross-wave reads below

    // coalesced BF store: 2 rows x 64 q x 64 ch f16 = 1024 int4
    for (int idx = tid; idx < 1024; idx += 256) {
        int rl2 = idx >> 9, rest = idx & 511;
        int ql = rest >> 3, seg = rest & 7;
        int4 v = *(const int4*)&sBF[(rl2 * 64 + ql) * 64 + ((seg ^ (ql & 7)) << 3)];
        *(int4*)(BF + (((b * 256 + r0 + rl2) * 256 + q0 + ql) * 64 + seg * 8)) = v;
    }

    // fused s2: one cell-row x 32 cells x 8 ch-groups; coalesced 64 B stores
    const int qp = tid >> 3, chg = tid & 7;
    {
        float dn[8], kp[8];
        #pragma unroll
        for (int j = 0; j < 8; ++j) { dn[j] = 0.f; kp[j] = 0.f; }
        #pragma unroll
        for (int u = 0; u < 2; ++u)
            #pragma unroll
            for (int v = 0; v < 2; ++v) {
                int rl = u, ql = 2 * qp + v;
                half8 bf = *(const half8*)(&sBF[(rl * 64 + ql) * 64 + ((chg ^ (ql & 7)) << 3)]);
                float2 p2 = *(const float2*)(pet + ((b * 256 + r0 + rl) * 256 + q0 + ql) * 16 + chg * 2);
                #pragma unroll
                for (int j = 0; j < 8; ++j) {
                    float bv = (float)bf[j];
                    dn[j] += bv;
                    kp[j] = fmaf((j < 4) ? p2.x : p2.y, bv, kp[j]);
                }
            }
        float* o = S2 + 2 * ((size_t)(((b * 128 + (r0 >> 1)) * 128 + (q0 >> 1) + qp) * 64) + chg * 8);
        #pragma unroll
        for (int m = 0; m < 4; ++m)
            *(float4*)(o + 4 * m) = make_float4(dn[2*m], kp[2*m], dn[2*m+1], kp[2*m+1]);
    }
}

// ---------------- ratio: j-paired — 2 outputs per thread, 6 shared loads/row ----------------
__global__ __launch_bounds__(256, 8)
void k_ratio(const float* __restrict__ S2, float* __restrict__ RATIO)
{
    int t = blockIdx.x * 256 + threadIdx.x;   // 3*64*32*64 threads
    int cf = t & 63;
    int j2 = (t >> 6) & 31;
    int i  = (t >> 11) & 63;
    int b  = t >> 17;
    float dn0 = 0.f, kp0 = 0.f, dn1 = 0.f, kp1 = 0.f;
    #pragma unroll
    for (int u = 0; u < 4; ++u) {
        int r2 = 2 * i - 1 + u;
        if ((unsigned)r2 >= 128u) continue;
        const float* rowp = S2 + 2 * (((size_t)(b * 128 + r2) * 128) * 64 + cf);
        float2 sv[6];
        #pragma unroll
        for (int tq = 0; tq < 6; ++tq) {
            int q2 = 4 * j2 - 1 + tq;
            sv[tq] = ((unsigned)q2 < 128u) ? *(const float2*)(rowp + q2 * 128)
                                           : make_float2(0.f, 0.f);
        }
        dn0 += sv[0].x; kp0 += sv[0].y;
        dn0 += sv[1].x; kp0 += sv[1].y;
        dn0 += sv[2].x; kp0 += sv[2].y;
        dn0 += sv[3].x; kp0 += sv[3].y;
        dn1 += sv[2].x; kp1 += sv[2].y;
        dn1 += sv[3].x; kp1 += sv[3].y;
        dn1 += sv[4].x; kp1 += sv[4].y;
        dn1 += sv[5].x; kp1 += sv[5].y;
    }
    size_t base = ((size_t)(b * 64 + i) * 64 + 2 * j2) * 64 + cf;
    RATIO[base]      = (dn0 == 0.f) ? 0.f : 0.25f * kp0 * __builtin_amdgcn_rcpf(dn0);
    RATIO[base + 64] = (dn1 == 0.f) ? 0.f : 0.25f * kp1 * __builtin_amdgcn_rcpf(dn1);
}

// ---------------- out: 4-row bands share one sU staging ----------------
__global__ __launch_bounds__(256, 4)
void k_out(const _Float16* __restrict__ BF, const float* __restrict__ RATIO,
           float* __restrict__ out)
{
    __shared__ __align__(16) float sU[64 * 68];   // [j][cf], row padded to 68
    const int tid = threadIdx.x;
    const int g = blockIdx.x % 65;
    const int b = blockIdx.x / 65;
    const int rf = (g == 0) ? 0 : 4 * g - 2;           // band first row
    const int nr = (g == 0 || g == 64) ? 2 : 4;        // band size

    const int i0 = (rf <= 253) ? 2 * ((rf + 2) >> 3)       : -1;
    const int i1 = (rf >= 2)   ? 2 * ((rf - 2) >> 3) + 1   : -1;

    for (int idx = tid; idx < 1024; idx += 256) {      // 1024 float4s
        int j = idx >> 4, c4 = idx & 15;
        float4 a = make_float4(0.f, 0.f, 0.f, 0.f);
        if (i0 >= 0) a = *(const float4*)&RATIO[(((b * 64 + i0) * 64 + j) << 6) + 4 * c4];
        float4 bb = make_float4(0.f, 0.f, 0.f, 0.f);
        if (i1 >= 0) bb = *(const float4*)&RATIO[(((b * 64 + i1) * 64 + j) << 6) + 4 * c4];
        *(float4*)&sU[j * 68 + 4 * c4] = make_float4(a.x + bb.x, a.y + bb.y, a.z + bb.z, a.w + bb.w);
    }
    __syncthreads();

    const int q = tid;
    const int j0 = (q <= 253) ? 2 * ((q + 2) >> 3)     : -1;
    const int j1 = (q >= 2)   ? 2 * ((q - 2) >> 3) + 1 : -1;

    for (int rr = 0; rr < nr; ++rr) {
        const int r = rf + rr;
        const half8* bfp = (const half8*)(BF + ((size_t)(b * 256 + r) * 256 + q) * 64);
        float o[16];
        #pragma unroll
        for (int c = 0; c < 16; ++c) o[c] = 0.f;

        #pragma unroll
        for (int c2 = 0; c2 < 8; ++c2) {
            half8 bf8 = bfp[c2];
            float s0 = 0.f, s1 = 0.f;
            #pragma unroll
            for (int pj = 0; pj < 2; ++pj) {
                int jj = pj ? j1 : j0;
                if (jj < 0) continue;
                const float* up = &sU[jj * 68 + 8 * c2];
                s0 += (float)bf8[0] * up[0] + (float)bf8[1] * up[1]
                    + (float)bf8[2] * up[2] + (float)bf8[3] * up[3];
                s1 += (float)bf8[4] * up[4] + (float)bf8[5] * up[5]
                    + (float)bf8[6] * up[6] + (float)bf8[7] * up[7];
            }
            o[2 * c2]     = s0;
            o[2 * c2 + 1] = s1;
        }
        float* op = out + ((size_t)(b * 256 + r) * 256 + q) * 16;
        #pragma unroll
        for (int m = 0; m < 4; ++m)
            *(float4*)(op + 4 * m) = make_float4(o[4*m], o[4*m+1], o[4*m+2], o[4*m+3]);
    }
}

extern "C" void kernel_launch(void* const* d_in, const int* in_sizes, int n_in,
                              void* d_out, int out_size, void* d_ws, size_t ws_size,
                              hipStream_t stream) {
    const float* mr  = (const float*)d_in[0];
    const float* pet = (const float*)d_in[1];
    const float* W1  = (const float*)d_in[2];
    const float* b1  = (const float*)d_in[3];
    const float* g1  = (const float*)d_in[4];
    const float* be1 = (const float*)d_in[5];
    const float* mu1 = (const float*)d_in[6];
    const float* v1  = (const float*)d_in[7];
    const float* W2  = (const float*)d_in[8];
    const float* b2  = (const float*)d_in[9];
    const float* g2  = (const float*)d_in[10];
    const float* be2 = (const float*)d_in[11];
    const float* mu2 = (const float*)d_in[12];
    const float* v2  = (const float*)d_in[13];

    // workspace layout (bytes):
    //   [0,        25165824)  BF  f16 (3*256*256*64)
    //   [25165824, 50331648)  S2  fp32 (3*128*128*64*2)
    //   [50331648, 53477376)  RATIO fp32 (3*64*64*64)
    //   [53477376, 53497856)  W1F f16
    //   [53497856, 53571584)  W2F f16
    //   [53571584, 53572608)  ST  fp32
    char* ws = (char*)d_ws;
    _Float16* BF    = (_Float16*)(ws);
    float*    S2    = (float*)(ws + 25165824);
    float*    RATIO = (float*)(ws + 50331648);
    _Float16* W1F   = (_Float16*)(ws + 53477376);
    _Float16* W2F   = (_Float16*)(ws + 53497856);
    float*    ST    = (float*)(ws + 53571584);
    float*    out   = (float*)d_out;

    dim3 blk(256);
    k_prep<<<185, blk, 0, stream>>>(W1, W2, b1, g1, be1, mu1, v1,
                                    b2, g2, be2, mu2, v2, W1F, W2F, ST);
    k_convf<<<dim3(512, 3), blk, 0, stream>>>(mr, W1F, W2F, ST, pet, BF, S2);
    k_ratio<<<1536, blk, 0, stream>>>(S2, RATIO);
    k_out<<<195, blk, 0, stream>>>(BF, RATIO, out);
}